// Round 6
// baseline (673.158 us; speedup 1.0000x reference)
//
#include <hip/hip_runtime.h>
#include <hip/hip_bf16.h>
#include <cstdint>
#include <cstddef>

#define NN  100000
#define EE  1600000
#define NE2 1700000
#define NBLK 391            // (NN+255)/256

#define OUT_X2    3200000   // NN*32 (start of edge_index region, f32 elements)
#define OUT_ALPHA 6600000   // NN*32 + 2*NE2 (start of alpha region)

__device__ __forceinline__ float lrelu(float v) { return v >= 0.f ? v : 0.2f * v; }

// ---------------------------------------------------------------------------
// GEMM1: h1 = x @ W1^T   ([NN,128] = [NN,128] @ [128,128]^T)
// ---------------------------------------------------------------------------
__global__ __launch_bounds__(256) void k_gemm1(
    const float* __restrict__ x, const float* __restrict__ W1,
    float* __restrict__ h1)
{
  __shared__ float Wt[128 * 128];   // Wt[f*128 + c] = W1[c*128 + f]
  __shared__ float xs[32 * 128];    // xs[r*128 + f]
  const int t = threadIdx.x;
  const int row0 = blockIdx.x * 32;

  {
    const float4* W4 = (const float4*)W1;
    #pragma unroll
    for (int i = 0; i < 16; ++i) {
      int idx4 = t * 16 + i;          // [0,4096)
      int c = idx4 >> 5, f4 = idx4 & 31;
      float4 v = W4[idx4];
      Wt[(4 * f4 + 0) * 128 + c] = v.x;
      Wt[(4 * f4 + 1) * 128 + c] = v.y;
      Wt[(4 * f4 + 2) * 128 + c] = v.z;
      Wt[(4 * f4 + 3) * 128 + c] = v.w;
    }
  }
  #pragma unroll
  for (int i = 0; i < 16; ++i) {      // 32 rows x 128 = 4096 = 16*256
    int idx = i * 256 + t;
    int r = idx >> 7, f = idx & 127;
    int grow = row0 + r;
    xs[r * 128 + f] = (grow < NN) ? x[(size_t)grow * 128 + f] : 0.f;
  }
  __syncthreads();

  const int cg = t & 31;
  const int rg = t >> 5;
  float acc[4][4];
  #pragma unroll
  for (int j = 0; j < 4; ++j)
    #pragma unroll
    for (int k = 0; k < 4; ++k) acc[j][k] = 0.f;

  const float4* Wt4 = (const float4*)Wt;
  #pragma unroll 4
  for (int f = 0; f < 128; ++f) {
    float4 wv = Wt4[f * 32 + cg];
    #pragma unroll
    for (int j = 0; j < 4; ++j) {
      float xv = xs[(4 * rg + j) * 128 + f];
      acc[j][0] += xv * wv.x; acc[j][1] += xv * wv.y;
      acc[j][2] += xv * wv.z; acc[j][3] += xv * wv.w;
    }
  }

  #pragma unroll
  for (int j = 0; j < 4; ++j) {
    int grow = row0 + 4 * rg + j;
    if (grow < NN)
      *(float4*)&h1[(size_t)grow * 128 + 4 * cg] =
          make_float4(acc[j][0], acc[j][1], acc[j][2], acc[j][3]);
  }
}

// ---------------------------------------------------------------------------
// attention logits layer 1
// ---------------------------------------------------------------------------
__global__ __launch_bounds__(256) void k_att1(
    const float* __restrict__ h1, const float* __restrict__ a_src,
    const float* __restrict__ a_dst,
    float* __restrict__ als, float* __restrict__ ald)
{
  int tid = blockIdx.x * 256 + threadIdx.x;
  int n = tid >> 3, h = tid & 7;
  const float4* hp = (const float4*)&h1[(size_t)n * 128 + h * 16];
  const float4* sp = (const float4*)&a_src[h * 16];
  const float4* dp = (const float4*)&a_dst[h * 16];
  float s = 0.f, d = 0.f;
  #pragma unroll
  for (int j = 0; j < 4; ++j) {
    float4 hv = hp[j], sv = sp[j], dv = dp[j];
    s += hv.x * sv.x + hv.y * sv.y + hv.z * sv.z + hv.w * sv.w;
    d += hv.x * dv.x + hv.y * dv.y + hv.z * dv.z + hv.w * dv.w;
  }
  als[(size_t)n * 8 + h] = s;
  ald[(size_t)n * 8 + h] = d;
}

// ---------------------------------------------------------------------------
// CSR build: degree histogram -> block scan -> global scan -> offsets+scatter
// ---------------------------------------------------------------------------
__global__ __launch_bounds__(256) void k_deg(
    const int* __restrict__ ei, int* __restrict__ deg)
{
  int i = blockIdx.x * 256 + threadIdx.x;
  if (i >= NE2) return;
  int dst = (i < EE) ? ei[EE + i] : (i - EE);
  atomicAdd(&deg[dst], 1);
}

__global__ __launch_bounds__(256) void k_scan1(
    const int* __restrict__ deg, int* __restrict__ bscan,
    int* __restrict__ partial)
{
  __shared__ int tmp[256];
  int t = threadIdx.x;
  int i = blockIdx.x * 256 + t;
  int v = (i < NN) ? deg[i] : 0;
  tmp[t] = v;
  __syncthreads();
  #pragma unroll
  for (int off = 1; off < 256; off <<= 1) {
    int add = (t >= off) ? tmp[t - off] : 0;
    __syncthreads();
    tmp[t] += add;
    __syncthreads();
  }
  if (i < NN) bscan[i] = tmp[t] - v;            // block-local exclusive
  if (t == 255) partial[blockIdx.x] = tmp[255]; // block total
}

__global__ __launch_bounds__(512) void k_scan2(
    const int* __restrict__ partial, int* __restrict__ pscan)
{
  __shared__ int tmp[512];
  int t = threadIdx.x;
  int v = (t < NBLK) ? partial[t] : 0;
  tmp[t] = v;
  __syncthreads();
  #pragma unroll
  for (int off = 1; off < 512; off <<= 1) {
    int add = (t >= off) ? tmp[t - off] : 0;
    __syncthreads();
    tmp[t] += add;
    __syncthreads();
  }
  if (t < NBLK) pscan[t] = tmp[t] - v;          // exclusive
}

__global__ __launch_bounds__(256) void k_scan3(
    const int* __restrict__ bscan, const int* __restrict__ pscan,
    int* __restrict__ base, int* __restrict__ cursor)
{
  int i = blockIdx.x * 256 + threadIdx.x;
  if (i < NN) {
    int b = bscan[i] + pscan[i >> 8];
    base[i] = b;
    cursor[i] = b;
  }
  if (i == 0) base[NN] = NE2;
}

__global__ __launch_bounds__(256) void k_scatter(
    const int* __restrict__ ei, int* __restrict__ cursor,
    int* __restrict__ csr_src)
{
  int i = blockIdx.x * 256 + threadIdx.x;
  if (i >= NE2) return;
  int src, dst;
  if (i < EE) { src = ei[i]; dst = ei[EE + i]; } else { src = dst = i - EE; }
  int pos = atomicAdd(&cursor[dst], 1);
  csr_src[pos] = src;
}

// ---------------------------------------------------------------------------
// layer-1 fused softmax+aggregate (atomic-free): one wave per node.
// out[n][c] = (sum_e w_e * h1[src_e][c]) / (sum_e w_e),  w_e = exp(lrelu(...))
// lane handles channels {2*lane, 2*lane+1}; head h = lane>>3.
// (max-shift skipped: softmax is shift-invariant; e = O(10) -> f32-safe)
// ---------------------------------------------------------------------------
__global__ __launch_bounds__(256) void k_node1(
    const int* __restrict__ base, const int* __restrict__ csr_src,
    const float* __restrict__ als, const float* __restrict__ ald,
    const float* __restrict__ h1, float* __restrict__ out)
{
  int wid = (blockIdx.x * 256 + threadIdx.x) >> 6;   // node; grid exact
  int lane = threadIdx.x & 63;
  int h = lane >> 3;
  float ad = ald[(size_t)wid * 8 + h];
  int s0 = base[wid], s1 = base[wid + 1];
  float ax = 0.f, ay = 0.f, sw = 0.f;
  for (int i = s0; i < s1; ++i) {
    int src = csr_src[i];                            // wave-uniform broadcast
    float w = __expf(lrelu(als[(size_t)src * 8 + h] + ad));
    float2 hv = *(const float2*)&h1[(size_t)src * 128 + 2 * lane];
    ax += w * hv.x; ay += w * hv.y; sw += w;
  }
  float inv = 1.f / (sw + 1e-16f);
  *(float2*)&out[(size_t)wid * 128 + 2 * lane] = make_float2(ax * inv, ay * inv);
}

// ---------------------------------------------------------------------------
// GEMM2: h2 = relu(acc1 + b1) @ W2^T   ([NN,32])
// ---------------------------------------------------------------------------
__global__ __launch_bounds__(256) void k_gemm2(
    const float* __restrict__ acc1, const float* __restrict__ b1,
    const float* __restrict__ W2, float* __restrict__ h2)
{
  __shared__ float Wt[128 * 32];    // Wt[f*32 + c] = W2[c*128 + f]
  __shared__ float xs[64 * 128];    // xs[r*128 + f]
  const int t = threadIdx.x;
  const int row0 = blockIdx.x * 64;

  {
    const float4* W4 = (const float4*)W2;
    #pragma unroll
    for (int i = 0; i < 4; ++i) {
      int idx4 = t * 4 + i;           // [0,1024)
      int c = idx4 >> 5, f4 = idx4 & 31;
      float4 v = W4[idx4];
      Wt[(4 * f4 + 0) * 32 + c] = v.x;
      Wt[(4 * f4 + 1) * 32 + c] = v.y;
      Wt[(4 * f4 + 2) * 32 + c] = v.z;
      Wt[(4 * f4 + 3) * 32 + c] = v.w;
    }
  }
  #pragma unroll
  for (int i = 0; i < 32; ++i) {      // 64 rows x 128 = 8192 = 32*256
    int idx = i * 256 + t;
    int r = idx >> 7, f = idx & 127;
    int grow = row0 + r;
    xs[r * 128 + f] =
        (grow < NN) ? fmaxf(acc1[(size_t)grow * 128 + f] + b1[f], 0.f) : 0.f;
  }
  __syncthreads();

  const int c = t & 31;
  const int rg = t >> 5;              // rows 8rg..8rg+7
  float acc[8];
  #pragma unroll
  for (int j = 0; j < 8; ++j) acc[j] = 0.f;

  #pragma unroll 4
  for (int f = 0; f < 128; ++f) {
    float wv = Wt[f * 32 + c];
    #pragma unroll
    for (int j = 0; j < 8; ++j)
      acc[j] += xs[(8 * rg + j) * 128 + f] * wv;
  }

  #pragma unroll
  for (int j = 0; j < 8; ++j) {
    int grow = row0 + 8 * rg + j;
    if (grow < NN) h2[(size_t)grow * 32 + c] = acc[j];
  }
}

// ---------------------------------------------------------------------------
// attention logits layer 2 (heads=1, K=32)
// ---------------------------------------------------------------------------
__global__ __launch_bounds__(256) void k_att2(
    const float* __restrict__ h2, const float* __restrict__ a_src,
    const float* __restrict__ a_dst,
    float* __restrict__ als, float* __restrict__ ald)
{
  int n = blockIdx.x * 256 + threadIdx.x;
  if (n >= NN) return;
  float s = 0.f, d = 0.f;
  #pragma unroll
  for (int j = 0; j < 8; ++j) {
    float4 hv = *(const float4*)&h2[(size_t)n * 32 + 4 * j];
    float4 sv = *(const float4*)&a_src[4 * j];
    float4 dv = *(const float4*)&a_dst[4 * j];
    s += hv.x * sv.x + hv.y * sv.y + hv.z * sv.z + hv.w * sv.w;
    d += hv.x * dv.x + hv.y * dv.y + hv.z * dv.z + hv.w * dv.w;
  }
  als[n] = s;
  ald[n] = d;
}

// ---------------------------------------------------------------------------
// layer-2 fused softmax+aggregate: half-wave (32 lanes) per node.
// Writes x2 (= agg + b2) directly into d_out; stores denominator s2.
// ---------------------------------------------------------------------------
__global__ __launch_bounds__(256) void k_node2(
    const int* __restrict__ base, const int* __restrict__ csr_src,
    const float* __restrict__ als, const float* __restrict__ ald,
    const float* __restrict__ h2, const float* __restrict__ b2,
    float* __restrict__ out_x2, float* __restrict__ s2)
{
  int node = (blockIdx.x * 256 + threadIdx.x) >> 5;  // grid exact
  int lane = threadIdx.x & 31;
  float ad = ald[node];
  int s0 = base[node], s1 = base[node + 1];
  float acc = 0.f, sw = 0.f;
  for (int i = s0; i < s1; ++i) {
    int src = csr_src[i];
    float w = __expf(lrelu(als[src] + ad));
    acc += w * h2[(size_t)src * 32 + lane];
    sw += w;
  }
  out_x2[(size_t)node * 32 + lane] = acc / (sw + 1e-16f) + b2[lane];
  if (lane == 0) s2[node] = sw;
}

// ---------------------------------------------------------------------------
// per-edge alpha output (layer 2) — pure gather, no atomics
// ---------------------------------------------------------------------------
__global__ __launch_bounds__(256) void k_alpha2(
    const int* __restrict__ ei, const float* __restrict__ als,
    const float* __restrict__ ald, const float* __restrict__ s2,
    float* __restrict__ outAlpha)
{
  int e = blockIdx.x * 256 + threadIdx.x;
  if (e >= NE2) return;
  int src, dst;
  if (e < EE) { src = ei[e]; dst = ei[EE + e]; } else { src = dst = e - EE; }
  float w = __expf(lrelu(als[src] + ald[dst]));
  outAlpha[e] = w / (s2[dst] + 1e-16f);
}

// ---------------------------------------------------------------------------
// edge_index_new as float into out[OUT_X2 .. OUT_X2+2*NE2)
// ---------------------------------------------------------------------------
__global__ __launch_bounds__(256) void k_edges(
    const int* __restrict__ ei, float* __restrict__ out)
{
  int j = blockIdx.x * 256 + threadIdx.x;
  if (j >= 2 * NE2) return;
  int r = (j >= NE2) ? 1 : 0;         // 0 = src row, 1 = dst row
  int k = j - r * NE2;
  int v = (k < EE) ? ei[r * EE + k] : (k - EE);
  out[OUT_X2 + j] = (float)v;
}

// ---------------------------------------------------------------------------
extern "C" void kernel_launch(void* const* d_in, const int* in_sizes, int n_in,
                              void* d_out, int out_size, void* d_ws, size_t ws_size,
                              hipStream_t stream)
{
  const float* x   = (const float*)d_in[0];
  const int*   ei  = (const int*)d_in[1];
  const float* W1  = (const float*)d_in[2];
  const float* as1 = (const float*)d_in[3];
  const float* ad1 = (const float*)d_in[4];
  const float* b1  = (const float*)d_in[5];
  const float* W2  = (const float*)d_in[6];
  const float* as2 = (const float*)d_in[7];
  const float* ad2 = (const float*)d_in[8];
  const float* b2  = (const float*)d_in[9];
  float* out = (float*)d_out;          // outputs are f32/int32 -> f32 buffer

  if (ws_size < 138800000) return;

  char* ws = (char*)d_ws;
  float* h1    = (float*)(ws + 0);            // [NN][128] 51.2 MB
  float* acc1  = (float*)(ws + 51200000);     // [NN][128] 51.2 MB
  float* als1  = (float*)(ws + 102400000);    // [NN][8]
  float* ald1  = (float*)(ws + 105600000);    // [NN][8]
  float* h2    = (float*)(ws + 108800000);    // [NN][32] 12.8 MB
  float* als2  = (float*)(ws + 121600000);    // [NN]
  float* ald2  = (float*)(ws + 122000000);    // [NN]
  float* s2    = (float*)(ws + 122400000);    // [NN]
  int*   deg   = (int*)(ws + 122800000);      // [NN]
  int*   bscan = (int*)(ws + 123200000);      // [NN]
  int*   part  = (int*)(ws + 123600000);      // [NBLK] (4 KB slot)
  int*   pscan = (int*)(ws + 123604096);      // [NBLK] (4 KB slot)
  int*   base  = (int*)(ws + 123608192);      // [NN+1]
  int*   cur   = (int*)(ws + 124008208);      // [NN]
  int*   csr   = (int*)(ws + 124408208);      // [NE2] 6.8 MB -> ends 131.2 MB

  hipMemsetAsync(deg, 0, 400000, stream);

  // CSR build (shared by both layers)
  k_deg    <<<(NE2 + 255) / 256, 256, 0, stream>>>(ei, deg);
  k_scan1  <<<NBLK, 256, 0, stream>>>(deg, bscan, part);
  k_scan2  <<<1, 512, 0, stream>>>(part, pscan);
  k_scan3  <<<NBLK, 256, 0, stream>>>(bscan, pscan, base, cur);
  k_scatter<<<(NE2 + 255) / 256, 256, 0, stream>>>(ei, cur, csr);

  // layer 1
  k_gemm1<<<(NN + 31) / 32, 256, 0, stream>>>(x, W1, h1);
  k_att1 <<<(NN * 8) / 256, 256, 0, stream>>>(h1, as1, ad1, als1, ald1);
  k_node1<<<(NN * 64) / 256, 256, 0, stream>>>(base, csr, als1, ald1, h1, acc1);

  // layer 2
  k_gemm2<<<(NN + 63) / 64, 256, 0, stream>>>(acc1, b1, W2, h2);
  k_att2 <<<(NN + 255) / 256, 256, 0, stream>>>(h2, as2, ad2, als2, ald2);
  k_node2<<<(NN * 32) / 256, 256, 0, stream>>>(base, csr, als2, ald2, h2, b2, out, s2);

  // edge outputs
  k_alpha2<<<(NE2 + 255) / 256, 256, 0, stream>>>(ei, als2, ald2, s2, out + OUT_ALPHA);
  k_edges <<<(2 * NE2 + 255) / 256, 256, 0, stream>>>(ei, out);
}

// Round 7
// 671.330 us; speedup vs baseline: 1.0027x; 1.0027x over previous
//
#include <hip/hip_runtime.h>
#include <hip/hip_bf16.h>
#include <cstdint>
#include <cstddef>

#define NN  100000
#define EE  1600000
#define NE2 1700000
#define NBLK 391            // (NN+255)/256

#define OUT_X2    3200000   // NN*32 (start of edge_index region, f32 elements)
#define OUT_ALPHA 6600000   // NN*32 + 2*NE2 (start of alpha region)

__device__ __forceinline__ float lrelu(float v) { return v >= 0.f ? v : 0.2f * v; }

// ---------------------------------------------------------------------------
// GEMM1: h1 = x @ W1^T   ([NN,128] = [NN,128] @ [128,128]^T)
// ---------------------------------------------------------------------------
__global__ __launch_bounds__(256) void k_gemm1(
    const float* __restrict__ x, const float* __restrict__ W1,
    float* __restrict__ h1)
{
  __shared__ float Wt[128 * 128];   // Wt[f*128 + c] = W1[c*128 + f]
  __shared__ float xs[32 * 128];    // xs[r*128 + f]
  const int t = threadIdx.x;
  const int row0 = blockIdx.x * 32;

  {
    const float4* W4 = (const float4*)W1;
    #pragma unroll
    for (int i = 0; i < 16; ++i) {
      int idx4 = t * 16 + i;          // [0,4096)
      int c = idx4 >> 5, f4 = idx4 & 31;
      float4 v = W4[idx4];
      Wt[(4 * f4 + 0) * 128 + c] = v.x;
      Wt[(4 * f4 + 1) * 128 + c] = v.y;
      Wt[(4 * f4 + 2) * 128 + c] = v.z;
      Wt[(4 * f4 + 3) * 128 + c] = v.w;
    }
  }
  #pragma unroll
  for (int i = 0; i < 16; ++i) {      // 32 rows x 128 = 4096 = 16*256
    int idx = i * 256 + t;
    int r = idx >> 7, f = idx & 127;
    int grow = row0 + r;
    xs[r * 128 + f] = (grow < NN) ? x[(size_t)grow * 128 + f] : 0.f;
  }
  __syncthreads();

  const int cg = t & 31;
  const int rg = t >> 5;
  float acc[4][4];
  #pragma unroll
  for (int j = 0; j < 4; ++j)
    #pragma unroll
    for (int k = 0; k < 4; ++k) acc[j][k] = 0.f;

  const float4* Wt4 = (const float4*)Wt;
  #pragma unroll 4
  for (int f = 0; f < 128; ++f) {
    float4 wv = Wt4[f * 32 + cg];
    #pragma unroll
    for (int j = 0; j < 4; ++j) {
      float xv = xs[(4 * rg + j) * 128 + f];
      acc[j][0] += xv * wv.x; acc[j][1] += xv * wv.y;
      acc[j][2] += xv * wv.z; acc[j][3] += xv * wv.w;
    }
  }

  #pragma unroll
  for (int j = 0; j < 4; ++j) {
    int grow = row0 + 4 * rg + j;
    if (grow < NN)
      *(float4*)&h1[(size_t)grow * 128 + 4 * cg] =
          make_float4(acc[j][0], acc[j][1], acc[j][2], acc[j][3]);
  }
}

// ---------------------------------------------------------------------------
// attention logits layer 1
// ---------------------------------------------------------------------------
__global__ __launch_bounds__(256) void k_att1(
    const float* __restrict__ h1, const float* __restrict__ a_src,
    const float* __restrict__ a_dst,
    float* __restrict__ als, float* __restrict__ ald)
{
  int tid = blockIdx.x * 256 + threadIdx.x;
  int n = tid >> 3, h = tid & 7;
  const float4* hp = (const float4*)&h1[(size_t)n * 128 + h * 16];
  const float4* sp = (const float4*)&a_src[h * 16];
  const float4* dp = (const float4*)&a_dst[h * 16];
  float s = 0.f, d = 0.f;
  #pragma unroll
  for (int j = 0; j < 4; ++j) {
    float4 hv = hp[j], sv = sp[j], dv = dp[j];
    s += hv.x * sv.x + hv.y * sv.y + hv.z * sv.z + hv.w * sv.w;
    d += hv.x * dv.x + hv.y * dv.y + hv.z * dv.z + hv.w * dv.w;
  }
  als[(size_t)n * 8 + h] = s;
  ald[(size_t)n * 8 + h] = d;
}

// ---------------------------------------------------------------------------
// CSR build: degree histogram -> block scan -> global scan -> offsets+scatter
// ---------------------------------------------------------------------------
__global__ __launch_bounds__(256) void k_deg(
    const int* __restrict__ ei, int* __restrict__ deg)
{
  int i = blockIdx.x * 256 + threadIdx.x;
  if (i >= NE2) return;
  int dst = (i < EE) ? ei[EE + i] : (i - EE);
  atomicAdd(&deg[dst], 1);
}

__global__ __launch_bounds__(256) void k_scan1(
    const int* __restrict__ deg, int* __restrict__ bscan,
    int* __restrict__ partial)
{
  __shared__ int tmp[256];
  int t = threadIdx.x;
  int i = blockIdx.x * 256 + t;
  int v = (i < NN) ? deg[i] : 0;
  tmp[t] = v;
  __syncthreads();
  #pragma unroll
  for (int off = 1; off < 256; off <<= 1) {
    int add = (t >= off) ? tmp[t - off] : 0;
    __syncthreads();
    tmp[t] += add;
    __syncthreads();
  }
  if (i < NN) bscan[i] = tmp[t] - v;            // block-local exclusive
  if (t == 255) partial[blockIdx.x] = tmp[255]; // block total
}

__global__ __launch_bounds__(512) void k_scan2(
    const int* __restrict__ partial, int* __restrict__ pscan)
{
  __shared__ int tmp[512];
  int t = threadIdx.x;
  int v = (t < NBLK) ? partial[t] : 0;
  tmp[t] = v;
  __syncthreads();
  #pragma unroll
  for (int off = 1; off < 512; off <<= 1) {
    int add = (t >= off) ? tmp[t - off] : 0;
    __syncthreads();
    tmp[t] += add;
    __syncthreads();
  }
  if (t < NBLK) pscan[t] = tmp[t] - v;          // exclusive
}

__global__ __launch_bounds__(256) void k_scan3(
    const int* __restrict__ bscan, const int* __restrict__ pscan,
    int* __restrict__ base, int* __restrict__ cursor)
{
  int i = blockIdx.x * 256 + threadIdx.x;
  if (i < NN) {
    int b = bscan[i] + pscan[i >> 8];
    base[i] = b;
    cursor[i] = b;
  }
  if (i == 0) base[NN] = NE2;
}

__global__ __launch_bounds__(256) void k_scatter(
    const int* __restrict__ ei, int* __restrict__ cursor,
    int* __restrict__ csr_src)
{
  int i = blockIdx.x * 256 + threadIdx.x;
  if (i >= NE2) return;
  int src, dst;
  if (i < EE) { src = ei[i]; dst = ei[EE + i]; } else { src = dst = i - EE; }
  int pos = atomicAdd(&cursor[dst], 1);
  csr_src[pos] = src;
}

// ---------------------------------------------------------------------------
// layer-1 fused softmax+aggregate (atomic-free): one wave per node.
// out[n][c] = (sum_e w_e * h1[src_e][c]) / (sum_e w_e),  w_e = exp(lrelu(...))
// lane handles channels {2*lane, 2*lane+1}; head h = lane>>3.
// (max-shift skipped: softmax is shift-invariant; e = O(10) -> f32-safe)
// ---------------------------------------------------------------------------
__global__ __launch_bounds__(256) void k_node1(
    const int* __restrict__ base, const int* __restrict__ csr_src,
    const float* __restrict__ als, const float* __restrict__ ald,
    const float* __restrict__ h1, float* __restrict__ out)
{
  int wid = (blockIdx.x * 256 + threadIdx.x) >> 6;   // node; grid exact
  int lane = threadIdx.x & 63;
  int h = lane >> 3;
  float ad = ald[(size_t)wid * 8 + h];
  int s0 = base[wid], s1 = base[wid + 1];
  float ax = 0.f, ay = 0.f, sw = 0.f;
  for (int i = s0; i < s1; ++i) {
    int src = csr_src[i];                            // wave-uniform broadcast
    float w = __expf(lrelu(als[(size_t)src * 8 + h] + ad));
    float2 hv = *(const float2*)&h1[(size_t)src * 128 + 2 * lane];
    ax += w * hv.x; ay += w * hv.y; sw += w;
  }
  float inv = 1.f / (sw + 1e-16f);
  *(float2*)&out[(size_t)wid * 128 + 2 * lane] = make_float2(ax * inv, ay * inv);
}

// ---------------------------------------------------------------------------
// GEMM2: h2 = relu(acc1 + b1) @ W2^T   ([NN,32])
// ---------------------------------------------------------------------------
__global__ __launch_bounds__(256) void k_gemm2(
    const float* __restrict__ acc1, const float* __restrict__ b1,
    const float* __restrict__ W2, float* __restrict__ h2)
{
  __shared__ float Wt[128 * 32];    // Wt[f*32 + c] = W2[c*128 + f]
  __shared__ float xs[64 * 128];    // xs[r*128 + f]
  const int t = threadIdx.x;
  const int row0 = blockIdx.x * 64;

  {
    const float4* W4 = (const float4*)W2;
    #pragma unroll
    for (int i = 0; i < 4; ++i) {
      int idx4 = t * 4 + i;           // [0,1024)
      int c = idx4 >> 5, f4 = idx4 & 31;
      float4 v = W4[idx4];
      Wt[(4 * f4 + 0) * 32 + c] = v.x;
      Wt[(4 * f4 + 1) * 32 + c] = v.y;
      Wt[(4 * f4 + 2) * 32 + c] = v.z;
      Wt[(4 * f4 + 3) * 32 + c] = v.w;
    }
  }
  #pragma unroll
  for (int i = 0; i < 32; ++i) {      // 64 rows x 128 = 8192 = 32*256
    int idx = i * 256 + t;
    int r = idx >> 7, f = idx & 127;
    int grow = row0 + r;
    xs[r * 128 + f] =
        (grow < NN) ? fmaxf(acc1[(size_t)grow * 128 + f] + b1[f], 0.f) : 0.f;
  }
  __syncthreads();

  const int c = t & 31;
  const int rg = t >> 5;              // rows 8rg..8rg+7
  float acc[8];
  #pragma unroll
  for (int j = 0; j < 8; ++j) acc[j] = 0.f;

  #pragma unroll 4
  for (int f = 0; f < 128; ++f) {
    float wv = Wt[f * 32 + c];
    #pragma unroll
    for (int j = 0; j < 8; ++j)
      acc[j] += xs[(8 * rg + j) * 128 + f] * wv;
  }

  #pragma unroll
  for (int j = 0; j < 8; ++j) {
    int grow = row0 + 8 * rg + j;
    if (grow < NN) h2[(size_t)grow * 32 + c] = acc[j];
  }
}

// ---------------------------------------------------------------------------
// attention logits layer 2 (heads=1, K=32)
// ---------------------------------------------------------------------------
__global__ __launch_bounds__(256) void k_att2(
    const float* __restrict__ h2, const float* __restrict__ a_src,
    const float* __restrict__ a_dst,
    float* __restrict__ als, float* __restrict__ ald)
{
  int n = blockIdx.x * 256 + threadIdx.x;
  if (n >= NN) return;
  float s = 0.f, d = 0.f;
  #pragma unroll
  for (int j = 0; j < 8; ++j) {
    float4 hv = *(const float4*)&h2[(size_t)n * 32 + 4 * j];
    float4 sv = *(const float4*)&a_src[4 * j];
    float4 dv = *(const float4*)&a_dst[4 * j];
    s += hv.x * sv.x + hv.y * sv.y + hv.z * sv.z + hv.w * sv.w;
    d += hv.x * dv.x + hv.y * dv.y + hv.z * dv.z + hv.w * dv.w;
  }
  als[n] = s;
  ald[n] = d;
}

// ---------------------------------------------------------------------------
// layer-2 fused softmax+aggregate: half-wave (32 lanes) per node.
// Writes x2 (= agg + b2) directly into d_out; stores denominator s2.
// ---------------------------------------------------------------------------
__global__ __launch_bounds__(256) void k_node2(
    const int* __restrict__ base, const int* __restrict__ csr_src,
    const float* __restrict__ als, const float* __restrict__ ald,
    const float* __restrict__ h2, const float* __restrict__ b2,
    float* __restrict__ out_x2, float* __restrict__ s2)
{
  int node = (blockIdx.x * 256 + threadIdx.x) >> 5;  // grid exact
  int lane = threadIdx.x & 31;
  float ad = ald[node];
  int s0 = base[node], s1 = base[node + 1];
  float acc = 0.f, sw = 0.f;
  for (int i = s0; i < s1; ++i) {
    int src = csr_src[i];
    float w = __expf(lrelu(als[src] + ad));
    acc += w * h2[(size_t)src * 32 + lane];
    sw += w;
  }
  out_x2[(size_t)node * 32 + lane] = acc / (sw + 1e-16f) + b2[lane];
  if (lane == 0) s2[node] = sw;
}

// ---------------------------------------------------------------------------
// per-edge alpha output (layer 2) — pure gather, no atomics
// ---------------------------------------------------------------------------
__global__ __launch_bounds__(256) void k_alpha2(
    const int* __restrict__ ei, const float* __restrict__ als,
    const float* __restrict__ ald, const float* __restrict__ s2,
    float* __restrict__ outAlpha)
{
  int e = blockIdx.x * 256 + threadIdx.x;
  if (e >= NE2) return;
  int src, dst;
  if (e < EE) { src = ei[e]; dst = ei[EE + e]; } else { src = dst = e - EE; }
  float w = __expf(lrelu(als[src] + ald[dst]));
  outAlpha[e] = w / (s2[dst] + 1e-16f);
}

// ---------------------------------------------------------------------------
// edge_index_new as float into out[OUT_X2 .. OUT_X2+2*NE2)
// ---------------------------------------------------------------------------
__global__ __launch_bounds__(256) void k_edges(
    const int* __restrict__ ei, float* __restrict__ out)
{
  int j = blockIdx.x * 256 + threadIdx.x;
  if (j >= 2 * NE2) return;
  int r = (j >= NE2) ? 1 : 0;         // 0 = src row, 1 = dst row
  int k = j - r * NE2;
  int v = (k < EE) ? ei[r * EE + k] : (k - EE);
  out[OUT_X2 + j] = (float)v;
}

// ---------------------------------------------------------------------------
extern "C" void kernel_launch(void* const* d_in, const int* in_sizes, int n_in,
                              void* d_out, int out_size, void* d_ws, size_t ws_size,
                              hipStream_t stream)
{
  const float* x   = (const float*)d_in[0];
  const int*   ei  = (const int*)d_in[1];
  const float* W1  = (const float*)d_in[2];
  const float* as1 = (const float*)d_in[3];
  const float* ad1 = (const float*)d_in[4];
  const float* b1  = (const float*)d_in[5];
  const float* W2  = (const float*)d_in[6];
  const float* as2 = (const float*)d_in[7];
  const float* ad2 = (const float*)d_in[8];
  const float* b2  = (const float*)d_in[9];
  float* out = (float*)d_out;          // outputs are f32/int32 -> f32 buffer

  if (ws_size < 138800000) return;

  char* ws = (char*)d_ws;
  float* h1    = (float*)(ws + 0);            // [NN][128] 51.2 MB
  float* acc1  = (float*)(ws + 51200000);     // [NN][128] 51.2 MB
  float* als1  = (float*)(ws + 102400000);    // [NN][8]
  float* ald1  = (float*)(ws + 105600000);    // [NN][8]
  float* h2    = (float*)(ws + 108800000);    // [NN][32] 12.8 MB
  float* als2  = (float*)(ws + 121600000);    // [NN]
  float* ald2  = (float*)(ws + 122000000);    // [NN]
  float* s2    = (float*)(ws + 122400000);    // [NN]
  int*   deg   = (int*)(ws + 122800000);      // [NN]
  int*   bscan = (int*)(ws + 123200000);      // [NN]
  int*   part  = (int*)(ws + 123600000);      // [NBLK] (4 KB slot)
  int*   pscan = (int*)(ws + 123604096);      // [NBLK] (4 KB slot)
  int*   base  = (int*)(ws + 123608192);      // [NN+1]
  int*   cur   = (int*)(ws + 124008208);      // [NN]
  int*   csr   = (int*)(ws + 124408208);      // [NE2] 6.8 MB -> ends 131.2 MB

  hipMemsetAsync(deg, 0, 400000, stream);

  // CSR build (shared by both layers)
  k_deg    <<<(NE2 + 255) / 256, 256, 0, stream>>>(ei, deg);
  k_scan1  <<<NBLK, 256, 0, stream>>>(deg, bscan, part);
  k_scan2  <<<1, 512, 0, stream>>>(part, pscan);
  k_scan3  <<<NBLK, 256, 0, stream>>>(bscan, pscan, base, cur);
  k_scatter<<<(NE2 + 255) / 256, 256, 0, stream>>>(ei, cur, csr);

  // layer 1
  k_gemm1<<<(NN + 31) / 32, 256, 0, stream>>>(x, W1, h1);
  k_att1 <<<(NN * 8) / 256, 256, 0, stream>>>(h1, as1, ad1, als1, ald1);
  k_node1<<<(NN * 64) / 256, 256, 0, stream>>>(base, csr, als1, ald1, h1, acc1);

  // layer 2
  k_gemm2<<<(NN + 63) / 64, 256, 0, stream>>>(acc1, b1, W2, h2);
  k_att2 <<<(NN + 255) / 256, 256, 0, stream>>>(h2, as2, ad2, als2, ald2);
  k_node2<<<(NN * 32) / 256, 256, 0, stream>>>(base, csr, als2, ald2, h2, b2, out, s2);

  // edge outputs
  k_alpha2<<<(NE2 + 255) / 256, 256, 0, stream>>>(ei, als2, ald2, s2, out + OUT_ALPHA);
  k_edges <<<(2 * NE2 + 255) / 256, 256, 0, stream>>>(ei, out);
}

// Round 9
// 554.586 us; speedup vs baseline: 1.2138x; 1.2105x over previous
//
#include <hip/hip_runtime.h>
#include <hip/hip_bf16.h>
#include <cstdint>
#include <cstddef>

#define NN  100000
#define EE  1600000
#define NE2 1700000
#define NBLK 391            // (NN+255)/256

#define OUT_X2    3200000   // NN*32 (start of edge_index region, f32 elements)
#define OUT_ALPHA 6600000   // NN*32 + 2*NE2 (start of alpha region)

__device__ __forceinline__ float lrelu(float v) { return v >= 0.f ? v : 0.2f * v; }

// bf16 pack/unpack (RNE round; unpack is shift/mask only)
__device__ __forceinline__ unsigned bf16_1(float x) {
  unsigned u = __float_as_uint(x);
  return (u + 0x7FFFu + ((u >> 16) & 1u)) >> 16;
}
__device__ __forceinline__ unsigned packbf(float lo, float hi) {
  return bf16_1(lo) | (bf16_1(hi) << 16);
}
__device__ __forceinline__ float unlo(unsigned u) { return __uint_as_float(u << 16); }
__device__ __forceinline__ float unhi(unsigned u) { return __uint_as_float(u & 0xFFFF0000u); }

// ---------------------------------------------------------------------------
// GEMM1: h1 = x @ W1^T ([NN,128]) in f32 math; writes h1 as packed bf16 and
// fused attention logits als/ald (head h = cg>>2; a vectors indexed 4cg+k).
// grid exact: 100000/32 = 3125 blocks.
// ---------------------------------------------------------------------------
__global__ __launch_bounds__(256) void k_gemm1(
    const float* __restrict__ x, const float* __restrict__ W1,
    const float* __restrict__ a_src, const float* __restrict__ a_dst,
    unsigned* __restrict__ h1b, float* __restrict__ als, float* __restrict__ ald)
{
  __shared__ float Wt[128 * 128];   // Wt[f*128 + c] = W1[c*128 + f]
  __shared__ float xs[32 * 128];    // xs[r*128 + f]
  const int t = threadIdx.x;
  const int row0 = blockIdx.x * 32;

  {
    const float4* W4 = (const float4*)W1;
    #pragma unroll
    for (int i = 0; i < 16; ++i) {
      int idx4 = t * 16 + i;          // [0,4096)
      int c = idx4 >> 5, f4 = idx4 & 31;
      float4 v = W4[idx4];
      Wt[(4 * f4 + 0) * 128 + c] = v.x;
      Wt[(4 * f4 + 1) * 128 + c] = v.y;
      Wt[(4 * f4 + 2) * 128 + c] = v.z;
      Wt[(4 * f4 + 3) * 128 + c] = v.w;
    }
  }
  #pragma unroll
  for (int i = 0; i < 16; ++i) {      // 32 rows x 128
    int idx = i * 256 + t;
    int r = idx >> 7, f = idx & 127;
    xs[r * 128 + f] = x[(size_t)(row0 + r) * 128 + f];
  }
  __syncthreads();

  const int cg = t & 31;              // cols 4cg..4cg+3
  const int rg = t >> 5;              // rows 4rg..4rg+3
  float acc[4][4];
  #pragma unroll
  for (int j = 0; j < 4; ++j)
    #pragma unroll
    for (int k = 0; k < 4; ++k) acc[j][k] = 0.f;

  const float4* Wt4 = (const float4*)Wt;
  #pragma unroll 4
  for (int f = 0; f < 128; ++f) {
    float4 wv = Wt4[f * 32 + cg];
    #pragma unroll
    for (int j = 0; j < 4; ++j) {
      float xv = xs[(4 * rg + j) * 128 + f];
      acc[j][0] += xv * wv.x; acc[j][1] += xv * wv.y;
      acc[j][2] += xv * wv.z; acc[j][3] += xv * wv.w;
    }
  }

  // epilogue: bf16 store + fused logits (shfl over 4 aligned lanes)
  float4 sA = ((const float4*)a_src)[cg];
  float4 dA = ((const float4*)a_dst)[cg];
  uint2* h1b2 = (uint2*)h1b;
  #pragma unroll
  for (int j = 0; j < 4; ++j) {
    int grow = row0 + 4 * rg + j;
    h1b2[(size_t)grow * 32 + cg] =
        make_uint2(packbf(acc[j][0], acc[j][1]), packbf(acc[j][2], acc[j][3]));
    float ps = acc[j][0] * sA.x + acc[j][1] * sA.y + acc[j][2] * sA.z + acc[j][3] * sA.w;
    float pd = acc[j][0] * dA.x + acc[j][1] * dA.y + acc[j][2] * dA.z + acc[j][3] * dA.w;
    ps += __shfl_xor(ps, 1); ps += __shfl_xor(ps, 2);
    pd += __shfl_xor(pd, 1); pd += __shfl_xor(pd, 2);
    if ((cg & 3) == 0) {
      als[(size_t)grow * 8 + (cg >> 2)] = ps;
      ald[(size_t)grow * 8 + (cg >> 2)] = pd;
    }
  }
}

// ---------------------------------------------------------------------------
// CSR build: degree histogram -> block scan -> global scan -> offsets+scatter
// ---------------------------------------------------------------------------
__global__ __launch_bounds__(256) void k_deg(
    const int* __restrict__ ei, int* __restrict__ deg)
{
  int i = blockIdx.x * 256 + threadIdx.x;
  if (i >= NE2) return;
  int dst = (i < EE) ? ei[EE + i] : (i - EE);
  atomicAdd(&deg[dst], 1);
}

__global__ __launch_bounds__(256) void k_scan1(
    const int* __restrict__ deg, int* __restrict__ bscan,
    int* __restrict__ partial)
{
  __shared__ int tmp[256];
  int t = threadIdx.x;
  int i = blockIdx.x * 256 + t;
  int v = (i < NN) ? deg[i] : 0;
  tmp[t] = v;
  __syncthreads();
  #pragma unroll
  for (int off = 1; off < 256; off <<= 1) {
    int add = (t >= off) ? tmp[t - off] : 0;
    __syncthreads();
    tmp[t] += add;
    __syncthreads();
  }
  if (i < NN) bscan[i] = tmp[t] - v;
  if (t == 255) partial[blockIdx.x] = tmp[255];
}

__global__ __launch_bounds__(512) void k_scan2(
    const int* __restrict__ partial, int* __restrict__ pscan)
{
  __shared__ int tmp[512];
  int t = threadIdx.x;
  int v = (t < NBLK) ? partial[t] : 0;
  tmp[t] = v;
  __syncthreads();
  #pragma unroll
  for (int off = 1; off < 512; off <<= 1) {
    int add = (t >= off) ? tmp[t - off] : 0;
    __syncthreads();
    tmp[t] += add;
    __syncthreads();
  }
  if (t < NBLK) pscan[t] = tmp[t] - v;
}

__global__ __launch_bounds__(256) void k_scan3(
    const int* __restrict__ bscan, const int* __restrict__ pscan,
    int* __restrict__ base, int* __restrict__ cursor)
{
  int i = blockIdx.x * 256 + threadIdx.x;
  if (i < NN) {
    int b = bscan[i] + pscan[i >> 8];
    base[i] = b;
    cursor[i] = b;
  }
  if (i == 0) base[NN] = NE2;
}

__global__ __launch_bounds__(256) void k_scatter(
    const int* __restrict__ ei, int* __restrict__ cursor,
    int* __restrict__ csr_src)
{
  int i = blockIdx.x * 256 + threadIdx.x;
  if (i >= NE2) return;
  int src, dst;
  if (i < EE) { src = ei[i]; dst = ei[EE + i]; } else { src = dst = i - EE; }
  int pos = atomicAdd(&cursor[dst], 1);
  csr_src[pos] = src;
}

// ---------------------------------------------------------------------------
// layer-1 fused softmax+aggregate: one wave/node, bf16 gather (256 B/edge).
// lane -> channels {2lane, 2lane+1}; head h = lane>>3. Output bf16 acc1.
// grid exact: NN*64/256 = 25000 blocks.
// ---------------------------------------------------------------------------
__global__ __launch_bounds__(256) void k_node1(
    const int* __restrict__ base, const int* __restrict__ csr_src,
    const float* __restrict__ als, const float* __restrict__ ald,
    const unsigned* __restrict__ h1b, unsigned* __restrict__ acc1b)
{
  int wid = (blockIdx.x * 256 + threadIdx.x) >> 6;
  int lane = threadIdx.x & 63;
  int h = lane >> 3;
  float ad = ald[(size_t)wid * 8 + h];
  int s0 = base[wid], s1 = base[wid + 1];
  float ax = 0.f, ay = 0.f, sw = 0.f;
  for (int i = s0; i < s1; ++i) {
    int src = csr_src[i];
    float w = __expf(lrelu(als[(size_t)src * 8 + h] + ad));
    unsigned u = h1b[(size_t)src * 64 + lane];
    ax += w * unlo(u); ay += w * unhi(u); sw += w;
  }
  float inv = 1.f / (sw + 1e-16f);
  acc1b[(size_t)wid * 64 + lane] = packbf(ax * inv, ay * inv);
}

// ---------------------------------------------------------------------------
// GEMM2: h2 = relu(acc1 + b1) @ W2^T ([NN,32]); bf16 in, bf16 out.
// thread: c2 = t&15 -> cols {2c2,2c2+1}; rg = t>>4 -> rows 4rg..4rg+3.
// ---------------------------------------------------------------------------
__global__ __launch_bounds__(256) void k_gemm2(
    const unsigned* __restrict__ acc1b, const float* __restrict__ b1,
    const float* __restrict__ W2, unsigned* __restrict__ h2b)
{
  __shared__ float Wt[128 * 32];    // Wt[f*32 + c] = W2[c*128 + f]
  __shared__ float xs[64 * 128];    // xs[r*128 + f]
  const int t = threadIdx.x;
  const int row0 = blockIdx.x * 64;

  {
    const float4* W4 = (const float4*)W2;
    #pragma unroll
    for (int i = 0; i < 4; ++i) {
      int idx4 = t * 4 + i;           // [0,1024)
      int c = idx4 >> 5, f4 = idx4 & 31;
      float4 v = W4[idx4];
      Wt[(4 * f4 + 0) * 32 + c] = v.x;
      Wt[(4 * f4 + 1) * 32 + c] = v.y;
      Wt[(4 * f4 + 2) * 32 + c] = v.z;
      Wt[(4 * f4 + 3) * 32 + c] = v.w;
    }
  }
  const float2* b2p = (const float2*)b1;
  #pragma unroll
  for (int i = 0; i < 16; ++i) {      // 64 rows x 64 uints
    int idx = i * 256 + t;
    int r = idx >> 6, u = idx & 63;
    int grow = row0 + r;
    unsigned v = (grow < NN) ? acc1b[(size_t)grow * 64 + u] : 0u;
    float2 bb = b2p[u];
    xs[r * 128 + 2 * u]     = fmaxf(unlo(v) + bb.x, 0.f);
    xs[r * 128 + 2 * u + 1] = fmaxf(unhi(v) + bb.y, 0.f);
  }
  __syncthreads();

  const int c2 = t & 15;              // cols 2c2, 2c2+1
  const int rg = t >> 4;              // rows 4rg..4rg+3
  float acc[4][2];
  #pragma unroll
  for (int j = 0; j < 4; ++j) { acc[j][0] = 0.f; acc[j][1] = 0.f; }

  const float2* Wt2 = (const float2*)Wt;
  #pragma unroll 4
  for (int f = 0; f < 128; ++f) {
    float2 wv = Wt2[f * 16 + c2];
    #pragma unroll
    for (int j = 0; j < 4; ++j) {
      float xv = xs[(4 * rg + j) * 128 + f];
      acc[j][0] += xv * wv.x; acc[j][1] += xv * wv.y;
    }
  }

  #pragma unroll
  for (int j = 0; j < 4; ++j) {
    int grow = row0 + 4 * rg + j;
    if (grow < NN)
      h2b[(size_t)grow * 16 + c2] = packbf(acc[j][0], acc[j][1]);
  }
}

// ---------------------------------------------------------------------------
// attention logits layer 2 (heads=1, K=32), bf16 h2
// ---------------------------------------------------------------------------
__global__ __launch_bounds__(256) void k_att2(
    const unsigned* __restrict__ h2b, const float* __restrict__ a_src,
    const float* __restrict__ a_dst,
    float* __restrict__ als, float* __restrict__ ald)
{
  int n = blockIdx.x * 256 + threadIdx.x;
  if (n >= NN) return;
  const float2* sp = (const float2*)a_src;
  const float2* dp = (const float2*)a_dst;
  float s = 0.f, d = 0.f;
  #pragma unroll
  for (int j = 0; j < 16; ++j) {
    unsigned u = h2b[(size_t)n * 16 + j];
    float x0 = unlo(u), x1 = unhi(u);
    float2 sv = sp[j], dv = dp[j];
    s += x0 * sv.x + x1 * sv.y;
    d += x0 * dv.x + x1 * dv.y;
  }
  als[n] = s;
  ald[n] = d;
}

// ---------------------------------------------------------------------------
// layer-2 fused softmax+aggregate: 16 lanes/node, bf16 gather (64 B/edge).
// Writes x2 (= agg + b2) into d_out; stores denominator s2.
// grid exact: NN*16/256 = 6250 blocks.
// ---------------------------------------------------------------------------
__global__ __launch_bounds__(256) void k_node2(
    const int* __restrict__ base, const int* __restrict__ csr_src,
    const float* __restrict__ als, const float* __restrict__ ald,
    const unsigned* __restrict__ h2b, const float* __restrict__ b2,
    float* __restrict__ out_x2, float* __restrict__ s2)
{
  int gid = blockIdx.x * 256 + threadIdx.x;
  int node = gid >> 4, q = gid & 15;
  float ad = ald[node];
  int s0 = base[node], s1 = base[node + 1];
  float ax = 0.f, ay = 0.f, sw = 0.f;
  for (int i = s0; i < s1; ++i) {
    int src = csr_src[i];
    float w = __expf(lrelu(als[src] + ad));
    unsigned u = h2b[(size_t)src * 16 + q];
    ax += w * unlo(u); ay += w * unhi(u); sw += w;
  }
  float inv = 1.f / (sw + 1e-16f);
  float2 bb = ((const float2*)b2)[q];
  ((float2*)out_x2)[(size_t)node * 16 + q] =
      make_float2(ax * inv + bb.x, ay * inv + bb.y);
  if (q == 0) s2[node] = sw;
}

// ---------------------------------------------------------------------------
// alpha (layer 2) + edge_index_new outputs, one ei pass.
// NOTE: takes the FULL out pointer; indexes absolute offsets.
// ---------------------------------------------------------------------------
__global__ __launch_bounds__(256) void k_alpha_edges(
    const int* __restrict__ ei, const float* __restrict__ als,
    const float* __restrict__ ald, const float* __restrict__ s2,
    float* __restrict__ out)
{
  int e = blockIdx.x * 256 + threadIdx.x;
  if (e >= NE2) return;
  int src, dst;
  if (e < EE) { src = ei[e]; dst = ei[EE + e]; } else { src = dst = e - EE; }
  float w = __expf(lrelu(als[src] + ald[dst]));
  out[OUT_ALPHA + e] = w / (s2[dst] + 1e-16f);
  out[OUT_X2 + e] = (float)src;
  out[OUT_X2 + NE2 + e] = (float)dst;
}

// ---------------------------------------------------------------------------
extern "C" void kernel_launch(void* const* d_in, const int* in_sizes, int n_in,
                              void* d_out, int out_size, void* d_ws, size_t ws_size,
                              hipStream_t stream)
{
  const float* x   = (const float*)d_in[0];
  const int*   ei  = (const int*)d_in[1];
  const float* W1  = (const float*)d_in[2];
  const float* as1 = (const float*)d_in[3];
  const float* ad1 = (const float*)d_in[4];
  const float* b1  = (const float*)d_in[5];
  const float* W2  = (const float*)d_in[6];
  const float* as2 = (const float*)d_in[7];
  const float* ad2 = (const float*)d_in[8];
  const float* b2  = (const float*)d_in[9];
  float* out = (float*)d_out;

  if (ws_size < 80000000) return;

  char* ws = (char*)d_ws;
  unsigned* h1b   = (unsigned*)(ws + 0);          // [NN][64] u32  25.6 MB
  unsigned* acc1b = (unsigned*)(ws + 25600000);   // [NN][64] u32  25.6 MB
  float*    als1  = (float*)(ws + 51200000);      // [NN][8]
  float*    ald1  = (float*)(ws + 54400000);      // [NN][8]
  unsigned* h2b   = (unsigned*)(ws + 57600000);   // [NN][16] u32  6.4 MB
  float*    als2  = (float*)(ws + 64000000);      // [NN]
  float*    ald2  = (float*)(ws + 64400000);      // [NN]
  float*    s2    = (float*)(ws + 64800000);      // [NN]
  int*      deg   = (int*)(ws + 65200000);        // [NN]
  int*      bscan = (int*)(ws + 65600000);        // [NN]
  int*      part  = (int*)(ws + 66000000);        // [NBLK]
  int*      pscan = (int*)(ws + 66004096);        // [NBLK]
  int*      base  = (int*)(ws + 66008192);        // [NN+1]
  int*      cur   = (int*)(ws + 66408208);        // [NN]
  int*      csr   = (int*)(ws + 66808208);        // [NE2] -> ends ~73.6 MB

  hipMemsetAsync(deg, 0, 400000, stream);

  // CSR build
  k_deg    <<<(NE2 + 255) / 256, 256, 0, stream>>>(ei, deg);
  k_scan1  <<<NBLK, 256, 0, stream>>>(deg, bscan, part);
  k_scan2  <<<1, 512, 0, stream>>>(part, pscan);
  k_scan3  <<<NBLK, 256, 0, stream>>>(bscan, pscan, base, cur);
  k_scatter<<<(NE2 + 255) / 256, 256, 0, stream>>>(ei, cur, csr);

  // layer 1
  k_gemm1<<<NN / 32, 256, 0, stream>>>(x, W1, as1, ad1, h1b, als1, ald1);
  k_node1<<<(NN * 64) / 256, 256, 0, stream>>>(base, csr, als1, ald1, h1b, acc1b);

  // layer 2
  k_gemm2<<<(NN + 63) / 64, 256, 0, stream>>>(acc1b, b1, W2, h2b);
  k_att2 <<<NBLK, 256, 0, stream>>>(h2b, as2, ad2, als2, ald2);
  k_node2<<<(NN * 16) / 256, 256, 0, stream>>>(base, csr, als2, ald2, h2b, b2, out, s2);

  // edge outputs
  k_alpha_edges<<<(NE2 + 255) / 256, 256, 0, stream>>>(ei, als2, ald2, s2, out);
}

// Round 10
// 443.972 us; speedup vs baseline: 1.5162x; 1.2491x over previous
//
#include <hip/hip_runtime.h>
#include <hip/hip_bf16.h>
#include <cstdint>
#include <cstddef>

#define NN  100000
#define EE  1600000
#define NE2 1700000
#define NBLK 391            // (NN+255)/256

#define OUT_X2    3200000   // NN*32 (start of edge_index region, f32 elements)
#define OUT_ALPHA 6600000   // NN*32 + 2*NE2 (start of alpha region)

__device__ __forceinline__ float lrelu(float v) { return v >= 0.f ? v : 0.2f * v; }

// bf16 pack/unpack (RNE round; unpack is shift/mask only)
__device__ __forceinline__ unsigned bf16_1(float x) {
  unsigned u = __float_as_uint(x);
  return (u + 0x7FFFu + ((u >> 16) & 1u)) >> 16;
}
__device__ __forceinline__ unsigned packbf(float lo, float hi) {
  return bf16_1(lo) | (bf16_1(hi) << 16);
}
__device__ __forceinline__ float unlo(unsigned u) { return __uint_as_float(u << 16); }
__device__ __forceinline__ float unhi(unsigned u) { return __uint_as_float(u & 0xFFFF0000u); }

// ---------------------------------------------------------------------------
// GEMM1: h1 = x @ W1^T ([NN,128]) in f32 math; writes h1 as packed bf16 and
// fused attention logits als/ald. grid exact: 100000/32 = 3125 blocks.
// ---------------------------------------------------------------------------
__global__ __launch_bounds__(256) void k_gemm1(
    const float* __restrict__ x, const float* __restrict__ W1,
    const float* __restrict__ a_src, const float* __restrict__ a_dst,
    unsigned* __restrict__ h1b, float* __restrict__ als, float* __restrict__ ald)
{
  __shared__ float Wt[128 * 128];   // Wt[f*128 + c] = W1[c*128 + f]
  __shared__ float xs[32 * 128];    // xs[r*128 + f]
  const int t = threadIdx.x;
  const int row0 = blockIdx.x * 32;

  {
    const float4* W4 = (const float4*)W1;
    #pragma unroll
    for (int i = 0; i < 16; ++i) {
      int idx4 = t * 16 + i;          // [0,4096)
      int c = idx4 >> 5, f4 = idx4 & 31;
      float4 v = W4[idx4];
      Wt[(4 * f4 + 0) * 128 + c] = v.x;
      Wt[(4 * f4 + 1) * 128 + c] = v.y;
      Wt[(4 * f4 + 2) * 128 + c] = v.z;
      Wt[(4 * f4 + 3) * 128 + c] = v.w;
    }
  }
  #pragma unroll
  for (int i = 0; i < 16; ++i) {      // 32 rows x 128
    int idx = i * 256 + t;
    int r = idx >> 7, f = idx & 127;
    xs[r * 128 + f] = x[(size_t)(row0 + r) * 128 + f];
  }
  __syncthreads();

  const int cg = t & 31;              // cols 4cg..4cg+3
  const int rg = t >> 5;              // rows 4rg..4rg+3
  float acc[4][4];
  #pragma unroll
  for (int j = 0; j < 4; ++j)
    #pragma unroll
    for (int k = 0; k < 4; ++k) acc[j][k] = 0.f;

  const float4* Wt4 = (const float4*)Wt;
  #pragma unroll 4
  for (int f = 0; f < 128; ++f) {
    float4 wv = Wt4[f * 32 + cg];
    #pragma unroll
    for (int j = 0; j < 4; ++j) {
      float xv = xs[(4 * rg + j) * 128 + f];
      acc[j][0] += xv * wv.x; acc[j][1] += xv * wv.y;
      acc[j][2] += xv * wv.z; acc[j][3] += xv * wv.w;
    }
  }

  // epilogue: bf16 store + fused logits (shfl over 4 aligned lanes)
  float4 sA = ((const float4*)a_src)[cg];
  float4 dA = ((const float4*)a_dst)[cg];
  uint2* h1b2 = (uint2*)h1b;
  #pragma unroll
  for (int j = 0; j < 4; ++j) {
    int grow = row0 + 4 * rg + j;
    h1b2[(size_t)grow * 32 + cg] =
        make_uint2(packbf(acc[j][0], acc[j][1]), packbf(acc[j][2], acc[j][3]));
    float ps = acc[j][0] * sA.x + acc[j][1] * sA.y + acc[j][2] * sA.z + acc[j][3] * sA.w;
    float pd = acc[j][0] * dA.x + acc[j][1] * dA.y + acc[j][2] * dA.z + acc[j][3] * dA.w;
    ps += __shfl_xor(ps, 1); ps += __shfl_xor(ps, 2);
    pd += __shfl_xor(pd, 1); pd += __shfl_xor(pd, 2);
    if ((cg & 3) == 0) {
      als[(size_t)grow * 8 + (cg >> 2)] = ps;
      ald[(size_t)grow * 8 + (cg >> 2)] = pd;
    }
  }
}

// ---------------------------------------------------------------------------
// CSR build: degree histogram -> block scan -> global scan -> offsets+scatter
// ---------------------------------------------------------------------------
__global__ __launch_bounds__(256) void k_deg(
    const int* __restrict__ ei, int* __restrict__ deg)
{
  int i = blockIdx.x * 256 + threadIdx.x;
  if (i >= NE2) return;
  int dst = (i < EE) ? ei[EE + i] : (i - EE);
  atomicAdd(&deg[dst], 1);
}

__global__ __launch_bounds__(256) void k_scan1(
    const int* __restrict__ deg, int* __restrict__ bscan,
    int* __restrict__ partial)
{
  __shared__ int tmp[256];
  int t = threadIdx.x;
  int i = blockIdx.x * 256 + t;
  int v = (i < NN) ? deg[i] : 0;
  tmp[t] = v;
  __syncthreads();
  #pragma unroll
  for (int off = 1; off < 256; off <<= 1) {
    int add = (t >= off) ? tmp[t - off] : 0;
    __syncthreads();
    tmp[t] += add;
    __syncthreads();
  }
  if (i < NN) bscan[i] = tmp[t] - v;
  if (t == 255) partial[blockIdx.x] = tmp[255];
}

__global__ __launch_bounds__(512) void k_scan2(
    const int* __restrict__ partial, int* __restrict__ pscan)
{
  __shared__ int tmp[512];
  int t = threadIdx.x;
  int v = (t < NBLK) ? partial[t] : 0;
  tmp[t] = v;
  __syncthreads();
  #pragma unroll
  for (int off = 1; off < 512; off <<= 1) {
    int add = (t >= off) ? tmp[t - off] : 0;
    __syncthreads();
    tmp[t] += add;
    __syncthreads();
  }
  if (t < NBLK) pscan[t] = tmp[t] - v;
}

__global__ __launch_bounds__(256) void k_scan3(
    const int* __restrict__ bscan, const int* __restrict__ pscan,
    int* __restrict__ base, int* __restrict__ cursor)
{
  int i = blockIdx.x * 256 + threadIdx.x;
  if (i < NN) {
    int b = bscan[i] + pscan[i >> 8];
    base[i] = b;
    cursor[i] = b;
  }
  if (i == 0) base[NN] = NE2;
}

__global__ __launch_bounds__(256) void k_scatter(
    const int* __restrict__ ei, int* __restrict__ cursor,
    int* __restrict__ csr_src)
{
  int i = blockIdx.x * 256 + threadIdx.x;
  if (i >= NE2) return;
  int src, dst;
  if (i < EE) { src = ei[i]; dst = ei[EE + i]; } else { src = dst = i - EE; }
  int pos = atomicAdd(&cursor[dst], 1);
  csr_src[pos] = src;
}

// ---------------------------------------------------------------------------
// layer-1 fused softmax+aggregate: one wave/node, bf16 gather (256 B/edge).
// Edge loop unrolled x4: 4 independent gather chains in flight (MLP).
// grid exact: NN*64/256 = 25000 blocks.
// ---------------------------------------------------------------------------
__global__ __launch_bounds__(256) void k_node1(
    const int* __restrict__ base, const int* __restrict__ csr_src,
    const float* __restrict__ als, const float* __restrict__ ald,
    const unsigned* __restrict__ h1b, unsigned* __restrict__ acc1b)
{
  int wid = (blockIdx.x * 256 + threadIdx.x) >> 6;
  int lane = threadIdx.x & 63;
  int h = lane >> 3;
  float ad = ald[(size_t)wid * 8 + h];
  int s0 = base[wid], s1 = base[wid + 1];
  float ax = 0.f, ay = 0.f, sw = 0.f;
  int i = s0;
  int n4 = s0 + ((s1 - s0) & ~3);
  for (; i < n4; i += 4) {
    int src0 = csr_src[i + 0];
    int src1 = csr_src[i + 1];
    int src2 = csr_src[i + 2];
    int src3 = csr_src[i + 3];
    float e0 = als[(size_t)src0 * 8 + h] + ad;
    float e1 = als[(size_t)src1 * 8 + h] + ad;
    float e2 = als[(size_t)src2 * 8 + h] + ad;
    float e3 = als[(size_t)src3 * 8 + h] + ad;
    unsigned u0 = h1b[(size_t)src0 * 64 + lane];
    unsigned u1 = h1b[(size_t)src1 * 64 + lane];
    unsigned u2 = h1b[(size_t)src2 * 64 + lane];
    unsigned u3 = h1b[(size_t)src3 * 64 + lane];
    float w0 = __expf(lrelu(e0));
    float w1 = __expf(lrelu(e1));
    float w2 = __expf(lrelu(e2));
    float w3 = __expf(lrelu(e3));
    ax += w0 * unlo(u0) + w1 * unlo(u1) + w2 * unlo(u2) + w3 * unlo(u3);
    ay += w0 * unhi(u0) + w1 * unhi(u1) + w2 * unhi(u2) + w3 * unhi(u3);
    sw += w0 + w1 + w2 + w3;
  }
  for (; i < s1; ++i) {
    int src = csr_src[i];
    float w = __expf(lrelu(als[(size_t)src * 8 + h] + ad));
    unsigned u = h1b[(size_t)src * 64 + lane];
    ax += w * unlo(u); ay += w * unhi(u); sw += w;
  }
  float inv = 1.f / (sw + 1e-16f);
  acc1b[(size_t)wid * 64 + lane] = packbf(ax * inv, ay * inv);
}

// ---------------------------------------------------------------------------
// GEMM2: h2 = relu(acc1 + b1) @ W2^T ([NN,32]); bf16 in, bf16 out.
// Fused layer-2 attention logits (als2/ald2) via 16-lane shfl reduce.
// ---------------------------------------------------------------------------
__global__ __launch_bounds__(256) void k_gemm2(
    const unsigned* __restrict__ acc1b, const float* __restrict__ b1,
    const float* __restrict__ W2, const float* __restrict__ a_src,
    const float* __restrict__ a_dst,
    unsigned* __restrict__ h2b, float* __restrict__ als, float* __restrict__ ald)
{
  __shared__ float Wt[128 * 32];    // Wt[f*32 + c] = W2[c*128 + f]
  __shared__ float xs[64 * 128];    // xs[r*128 + f]
  const int t = threadIdx.x;
  const int row0 = blockIdx.x * 64;

  {
    const float4* W4 = (const float4*)W2;
    #pragma unroll
    for (int i = 0; i < 4; ++i) {
      int idx4 = t * 4 + i;           // [0,1024)
      int c = idx4 >> 5, f4 = idx4 & 31;
      float4 v = W4[idx4];
      Wt[(4 * f4 + 0) * 32 + c] = v.x;
      Wt[(4 * f4 + 1) * 32 + c] = v.y;
      Wt[(4 * f4 + 2) * 32 + c] = v.z;
      Wt[(4 * f4 + 3) * 32 + c] = v.w;
    }
  }
  const float2* b2p = (const float2*)b1;
  #pragma unroll
  for (int i = 0; i < 16; ++i) {      // 64 rows x 64 uints
    int idx = i * 256 + t;
    int r = idx >> 6, u = idx & 63;
    int grow = row0 + r;
    unsigned v = (grow < NN) ? acc1b[(size_t)grow * 64 + u] : 0u;
    float2 bb = b2p[u];
    xs[r * 128 + 2 * u]     = fmaxf(unlo(v) + bb.x, 0.f);
    xs[r * 128 + 2 * u + 1] = fmaxf(unhi(v) + bb.y, 0.f);
  }
  __syncthreads();

  const int c2 = t & 15;              // cols 2c2, 2c2+1
  const int rg = t >> 4;              // rows 4rg..4rg+3
  float acc[4][2];
  #pragma unroll
  for (int j = 0; j < 4; ++j) { acc[j][0] = 0.f; acc[j][1] = 0.f; }

  const float2* Wt2 = (const float2*)Wt;
  #pragma unroll 4
  for (int f = 0; f < 128; ++f) {
    float2 wv = Wt2[f * 16 + c2];
    #pragma unroll
    for (int j = 0; j < 4; ++j) {
      float xv = xs[(4 * rg + j) * 128 + f];
      acc[j][0] += xv * wv.x; acc[j][1] += xv * wv.y;
    }
  }

  float2 sv = ((const float2*)a_src)[c2];
  float2 dv = ((const float2*)a_dst)[c2];
  #pragma unroll
  for (int j = 0; j < 4; ++j) {
    int grow = row0 + 4 * rg + j;
    if (grow < NN) {
      h2b[(size_t)grow * 16 + c2] = packbf(acc[j][0], acc[j][1]);
      float ps = acc[j][0] * sv.x + acc[j][1] * sv.y;
      float pd = acc[j][0] * dv.x + acc[j][1] * dv.y;
      ps += __shfl_xor(ps, 1); ps += __shfl_xor(ps, 2);
      ps += __shfl_xor(ps, 4); ps += __shfl_xor(ps, 8);
      pd += __shfl_xor(pd, 1); pd += __shfl_xor(pd, 2);
      pd += __shfl_xor(pd, 4); pd += __shfl_xor(pd, 8);
      if (c2 == 0) { als[grow] = ps; ald[grow] = pd; }
    }
  }
}

// ---------------------------------------------------------------------------
// layer-2 fused softmax+aggregate: 16 lanes/node, bf16 gather (64 B/edge).
// Edge loop unrolled x4. Writes x2 into d_out; stores denominator s2.
// grid exact: NN*16/256 = 6250 blocks.
// ---------------------------------------------------------------------------
__global__ __launch_bounds__(256) void k_node2(
    const int* __restrict__ base, const int* __restrict__ csr_src,
    const float* __restrict__ als, const float* __restrict__ ald,
    const unsigned* __restrict__ h2b, const float* __restrict__ b2,
    float* __restrict__ out_x2, float* __restrict__ s2)
{
  int gid = blockIdx.x * 256 + threadIdx.x;
  int node = gid >> 4, q = gid & 15;
  float ad = ald[node];
  int s0 = base[node], s1 = base[node + 1];
  float ax = 0.f, ay = 0.f, sw = 0.f;
  int i = s0;
  int n4 = s0 + ((s1 - s0) & ~3);
  for (; i < n4; i += 4) {
    int src0 = csr_src[i + 0];
    int src1 = csr_src[i + 1];
    int src2 = csr_src[i + 2];
    int src3 = csr_src[i + 3];
    float e0 = als[src0] + ad;
    float e1 = als[src1] + ad;
    float e2 = als[src2] + ad;
    float e3 = als[src3] + ad;
    unsigned u0 = h2b[(size_t)src0 * 16 + q];
    unsigned u1 = h2b[(size_t)src1 * 16 + q];
    unsigned u2 = h2b[(size_t)src2 * 16 + q];
    unsigned u3 = h2b[(size_t)src3 * 16 + q];
    float w0 = __expf(lrelu(e0));
    float w1 = __expf(lrelu(e1));
    float w2 = __expf(lrelu(e2));
    float w3 = __expf(lrelu(e3));
    ax += w0 * unlo(u0) + w1 * unlo(u1) + w2 * unlo(u2) + w3 * unlo(u3);
    ay += w0 * unhi(u0) + w1 * unhi(u1) + w2 * unhi(u2) + w3 * unhi(u3);
    sw += w0 + w1 + w2 + w3;
  }
  for (; i < s1; ++i) {
    int src = csr_src[i];
    float w = __expf(lrelu(als[src] + ad));
    unsigned u = h2b[(size_t)src * 16 + q];
    ax += w * unlo(u); ay += w * unhi(u); sw += w;
  }
  float inv = 1.f / (sw + 1e-16f);
  float2 bb = ((const float2*)b2)[q];
  ((float2*)out_x2)[(size_t)node * 16 + q] =
      make_float2(ax * inv + bb.x, ay * inv + bb.y);
  if (q == 0) s2[node] = sw;
}

// ---------------------------------------------------------------------------
// alpha (layer 2) + edge_index_new outputs, one ei pass (absolute offsets)
// ---------------------------------------------------------------------------
__global__ __launch_bounds__(256) void k_alpha_edges(
    const int* __restrict__ ei, const float* __restrict__ als,
    const float* __restrict__ ald, const float* __restrict__ s2,
    float* __restrict__ out)
{
  int e = blockIdx.x * 256 + threadIdx.x;
  if (e >= NE2) return;
  int src, dst;
  if (e < EE) { src = ei[e]; dst = ei[EE + e]; } else { src = dst = e - EE; }
  float w = __expf(lrelu(als[src] + ald[dst]));
  out[OUT_ALPHA + e] = w / (s2[dst] + 1e-16f);
  out[OUT_X2 + e] = (float)src;
  out[OUT_X2 + NE2 + e] = (float)dst;
}

// ---------------------------------------------------------------------------
extern "C" void kernel_launch(void* const* d_in, const int* in_sizes, int n_in,
                              void* d_out, int out_size, void* d_ws, size_t ws_size,
                              hipStream_t stream)
{
  const float* x   = (const float*)d_in[0];
  const int*   ei  = (const int*)d_in[1];
  const float* W1  = (const float*)d_in[2];
  const float* as1 = (const float*)d_in[3];
  const float* ad1 = (const float*)d_in[4];
  const float* b1  = (const float*)d_in[5];
  const float* W2  = (const float*)d_in[6];
  const float* as2 = (const float*)d_in[7];
  const float* ad2 = (const float*)d_in[8];
  const float* b2  = (const float*)d_in[9];
  float* out = (float*)d_out;

  if (ws_size < 80000000) return;

  char* ws = (char*)d_ws;
  unsigned* h1b   = (unsigned*)(ws + 0);          // [NN][64] u32  25.6 MB
  unsigned* acc1b = (unsigned*)(ws + 25600000);   // [NN][64] u32  25.6 MB
  float*    als1  = (float*)(ws + 51200000);      // [NN][8]
  float*    ald1  = (float*)(ws + 54400000);      // [NN][8]
  unsigned* h2b   = (unsigned*)(ws + 57600000);   // [NN][16] u32  6.4 MB
  float*    als2  = (float*)(ws + 64000000);      // [NN]
  float*    ald2  = (float*)(ws + 64400000);      // [NN]
  float*    s2    = (float*)(ws + 64800000);      // [NN]
  int*      deg   = (int*)(ws + 65200000);        // [NN]
  int*      bscan = (int*)(ws + 65600000);        // [NN]
  int*      part  = (int*)(ws + 66000000);        // [NBLK]
  int*      pscan = (int*)(ws + 66004096);        // [NBLK]
  int*      base  = (int*)(ws + 66008192);        // [NN+1]
  int*      cur   = (int*)(ws + 66408208);        // [NN]
  int*      csr   = (int*)(ws + 66808208);        // [NE2] -> ends ~73.6 MB

  hipMemsetAsync(deg, 0, 400000, stream);

  // CSR build
  k_deg    <<<(NE2 + 255) / 256, 256, 0, stream>>>(ei, deg);
  k_scan1  <<<NBLK, 256, 0, stream>>>(deg, bscan, part);
  k_scan2  <<<1, 512, 0, stream>>>(part, pscan);
  k_scan3  <<<NBLK, 256, 0, stream>>>(bscan, pscan, base, cur);
  k_scatter<<<(NE2 + 255) / 256, 256, 0, stream>>>(ei, cur, csr);

  // layer 1
  k_gemm1<<<NN / 32, 256, 0, stream>>>(x, W1, as1, ad1, h1b, als1, ald1);
  k_node1<<<(NN * 64) / 256, 256, 0, stream>>>(base, csr, als1, ald1, h1b, acc1b);

  // layer 2
  k_gemm2<<<(NN + 63) / 64, 256, 0, stream>>>(acc1b, b1, W2, as2, ad2, h2b, als2, ald2);
  k_node2<<<(NN * 16) / 256, 256, 0, stream>>>(base, csr, als2, ald2, h2b, b2, out, s2);

  // edge outputs
  k_alpha_edges<<<(NE2 + 255) / 256, 256, 0, stream>>>(ei, als2, ald2, s2, out);
}